// Round 5
// baseline (636.114 us; speedup 1.0000x reference)
//
#include <hip/hip_runtime.h>
#include <hip/hip_bf16.h>

#define B_ 8
#define N_ 4096
#define D_ 512
#define BM 64
#define BK 64
#define NTH 512
#define NT (N_ / BK)

typedef __attribute__((ext_vector_type(8))) short bf16x8;
typedef __attribute__((ext_vector_type(4))) float f32x4;
typedef __attribute__((ext_vector_type(16))) float f32x16;

__device__ __forceinline__ short f2bs(float x) {
  union { __hip_bfloat16 h; short s; } u;
  u.h = __float2bfloat16(x);
  return u.s;
}

__device__ __forceinline__ void gld16(const void* g, void* l) {
  __builtin_amdgcn_global_load_lds((const __attribute__((address_space(1))) void*)g,
                                   (__attribute__((address_space(3))) void*)l, 16, 0, 0);
}

// ---------------- kernel 1: rn[b*N+n] = 1/||tgt[b,n,:]|| ----------------
__global__ void __launch_bounds__(256) rnorm_kernel(const float* __restrict__ tgt,
                                                    float* __restrict__ rn) {
  int row  = blockIdx.x * 4 + (threadIdx.x >> 6);
  int lane = threadIdx.x & 63;
  const float* p = tgt + (size_t)row * D_ + lane * 8;
  float4 a = *(const float4*)p;
  float4 b = *(const float4*)(p + 4);
  float s = a.x*a.x + a.y*a.y + a.z*a.z + a.w*a.w
          + b.x*b.x + b.y*b.y + b.z*b.z + b.w*b.w;
  #pragma unroll
  for (int m = 32; m >= 1; m >>= 1) s += __shfl_xor(s, m, 64);
  if (lane == 0) rn[row] = rsqrtf(s);
}

// ---------------- kernel 2: prep layouts ----------------
// Tm2[b][n>>4][d>>3][n&15][d&7] = bf16( tgt[b][n][d] * rn[b][n] )  (normalized, frag-linear)
// Vt2[b][n>>3][d][n&7]          = bf16( tgt[b][n][d] )             (raw, m-granule)
__global__ void __launch_bounds__(256) prep_kernel(const float* __restrict__ tgt,
                                                   const float* __restrict__ rn,
                                                   ushort* __restrict__ Tm2,
                                                   ushort* __restrict__ Vt2) {
  __shared__ ushort L[64][72];                  // raw bf16 tile, padded
  const int id = blockIdx.x;                    // 8b x 64nt x 8dt
  const int b = id >> 9, nt = (id >> 3) & 63, dt = id & 7;
  const int n0 = nt * 64, d0 = dt * 64;
  const int t = threadIdx.x;
  const float* Tg  = tgt + ((size_t)b * N_ + n0) * D_ + d0;
  const float* rnb = rn + b * N_ + n0;
  ushort* T2 = Tm2 + (size_t)b * N_ * D_;
  ushort* V2 = Vt2 + (size_t)b * N_ * D_;

  const int r = t >> 3, gg = t & 7;             // row-half, d-granule (local)
  #pragma unroll
  for (int p = 0; p < 2; ++p) {
    int row = p * 32 + r;
    const float* src = Tg + (size_t)row * D_ + gg * 8;
    float4 f0 = *(const float4*)src;
    float4 f1 = *(const float4*)(src + 4);
    float sc = rnb[row];
    bf16x8 nv;
    nv[0]=f2bs(f0.x*sc); nv[1]=f2bs(f0.y*sc); nv[2]=f2bs(f0.z*sc); nv[3]=f2bs(f0.w*sc);
    nv[4]=f2bs(f1.x*sc); nv[5]=f2bs(f1.y*sc); nv[6]=f2bs(f1.z*sc); nv[7]=f2bs(f1.w*sc);
    // frag-linear: [(n0+row)>>4][dt*8+gg][row&15][8]
    *(bf16x8*)(T2 + (size_t)(n0/16 + (row >> 4)) * (D_ * 16)
                  + (dt * 8 + gg) * 128 + (row & 15) * 8) = nv;
    bf16x8 rv;
    rv[0]=f2bs(f0.x); rv[1]=f2bs(f0.y); rv[2]=f2bs(f0.z); rv[3]=f2bs(f0.w);
    rv[4]=f2bs(f1.x); rv[5]=f2bs(f1.y); rv[6]=f2bs(f1.z); rv[7]=f2bs(f1.w);
    #pragma unroll
    for (int e = 0; e < 8; ++e) L[row][gg*8 + e] = (ushort)rv[e];
  }
  __syncthreads();
  // transpose -> Vt2: task (ng, dd): 16B = L[ng*8 + j][dd], j=0..7
  #pragma unroll
  for (int p = 0; p < 2; ++p) {
    int task = p * 256 + t;
    int ng = task >> 6, dd = task & 63;
    bf16x8 v;
    #pragma unroll
    for (int j = 0; j < 8; ++j) v[j] = (short)L[ng*8 + j][dd];
    *(bf16x8*)(V2 + ((size_t)(n0/8 + ng) * D_ + d0 + dd) * 8) = v;
  }
}

// ---------------- kernel 3: fused  out = tanh(Xn Xn^T) * tgt ----------------
// BM=64 q-rows/block, 8 waves. S: 16x16x32, Q in regs (32 rows, 128 VGPR),
// B-frags DIRECT from L2 (frag-linear Tm2, contiguous 1KB/read). No KV tile.
// PV: 32x32x16, wave w owns d-cols [w*64,+64), V from LDS (VT), P from LDS (dbuf).
__global__ void __launch_bounds__(NTH, 2) fused_kernel(const ushort* __restrict__ Tm2,
                                                       const ushort* __restrict__ Vt2,
                                                       float* __restrict__ out) {
  __shared__ __align__(16) ushort VT[BK * D_];    // [m/8][d][8] raw     64 KB
  __shared__ __align__(16) ushort Pl[2][BM * BK]; // [m/8][q][8] dbuf  2x 8 KB

  const int id = blockIdx.x;             // 512 blocks
  const int b  = id & 7;                 // batch -> XCD round-robin
  const int q0 = (id >> 3) * BM;

  const int lane = threadIdx.x & 63;
  const int w    = threadIdx.x >> 6;

  const ushort* Tb2 = Tm2 + (size_t)b * N_ * D_;  // frag-linear normalized
  const ushort* Vb2 = Vt2 + (size_t)b * N_ * D_;  // [n/8][d][8] raw

  // ---- S mapping: wave -> q rows [qG*32,+32), m cols [mG*16,+16)
  const int qG = w >> 2;                 // 0..1
  const int mG = w & 3;                  // 0..3

  // Q fragments: 32 rows x 512 d = 128 VGPR
  bf16x8 qf[2][16];
  #pragma unroll
  for (int f = 0; f < 2; ++f) {
    const ushort* qb = Tb2 + (size_t)((q0 + qG * 32 + f * 16) >> 4) * (D_ * 16)
                     + (lane >> 4) * 128 + (lane & 15) * 8;
    #pragma unroll
    for (int kk = 0; kk < 16; ++kk)
      qf[f][kk] = *(const bf16x8*)(qb + kk * 512);
  }

  f32x16 acc[2][2] = {};                 // [qs][ds] : wave tile 64q x 64d

  // stage V-tile: VT[mg][d][e] <- Vb2[t*8+mg][d][e] ; wave w stages granule mg=w
  auto STAGE_VT = [&](int mt) {
    #pragma unroll
    for (int i = 0; i < 8; ++i)
      gld16(Vb2 + ((size_t)(mt * 8 + w) * D_) * 8 + i * 512 + lane * 8,
            &VT[w * 4096 + i * 512]);
  };

  STAGE_VT(0);

  for (int t = 0; t < NT; ++t) {
    const int m0 = t * BK;

    // ---- S = Qn * Kn^T : 32 MFMA, B-frags direct from L2 (contiguous 1KB/wave-read)
    f32x4 sacc[2] = {};
    {
      const ushort* bb = Tb2 + (size_t)(m0 / 16 + mG) * (D_ * 16)
                       + (lane >> 4) * 128 + (lane & 15) * 8;
      #pragma unroll
      for (int kk = 0; kk < 16; ++kk) {
        bf16x8 bfr = *(const bf16x8*)(bb + kk * 512);
        sacc[0] = __builtin_amdgcn_mfma_f32_16x16x32_bf16(qf[0][kk], bfr, sacc[0], 0, 0, 0);
        sacc[1] = __builtin_amdgcn_mfma_f32_16x16x32_bf16(qf[1][kk], bfr, sacc[1], 0, 0, 0);
      }
    }

    // ---- tanh -> Pl[t&1]  ([m/8][q][8])
    {
      ushort* P = Pl[t & 1];
      const int mm = mG * 16 + (lane & 15);
      #pragma unroll
      for (int f = 0; f < 2; ++f)
        #pragma unroll
        for (int j = 0; j < 4; ++j) {
          int ql = qG * 32 + f * 16 + (lane >> 4) * 4 + j;
          float e = __builtin_amdgcn_exp2f(sacc[f][j] * 2.885390082f);  // e^(2s)
          float tn = 1.0f - 2.0f * __builtin_amdgcn_rcpf(e + 1.0f);
          P[(mm >> 3) * 512 + ql * 8 + (mm & 7)] = (ushort)f2bs(tn);
        }
    }
    __syncthreads();                     // bar1: Pl visible; VT(t) drained (issued last iter)

    // ---- out += P * V : 16 MFMA-32x32, wave d-slice [w*64,+64)
    {
      const ushort* P = Pl[t & 1];
      #pragma unroll
      for (int ks = 0; ks < 4; ++ks) {
        int mg = ks * 2 + (lane >> 5);
        bf16x8 pa0 = *(const bf16x8*)&P[mg * 512 + (lane & 31) * 8];
        bf16x8 pa1 = *(const bf16x8*)&P[mg * 512 + (32 + (lane & 31)) * 8];
        bf16x8 vb0 = *(const bf16x8*)&VT[mg * 4096 + (w * 64 + (lane & 31)) * 8];
        bf16x8 vb1 = *(const bf16x8*)&VT[mg * 4096 + (w * 64 + 32 + (lane & 31)) * 8];
        acc[0][0] = __builtin_amdgcn_mfma_f32_32x32x16_bf16(pa0, vb0, acc[0][0], 0, 0, 0);
        acc[0][1] = __builtin_amdgcn_mfma_f32_32x32x16_bf16(pa0, vb1, acc[0][1], 0, 0, 0);
        acc[1][0] = __builtin_amdgcn_mfma_f32_32x32x16_bf16(pa1, vb0, acc[1][0], 0, 0, 0);
        acc[1][1] = __builtin_amdgcn_mfma_f32_32x32x16_bf16(pa1, vb1, acc[1][1], 0, 0, 0);
      }
    }
    __syncthreads();                     // bar2: PV(t) done -> VT free (drain-free)

    if (t < NT - 1) STAGE_VT(t + 1);     // lands during S(t+1), drained at bar1(t+1)
  }

  // ---- write out [64 x 512] fp32; C/D 32x32: row=(reg&3)+8*(reg>>2)+4*(lane>>5)
  {
    float* op = out + (size_t)b * N_ * D_ + (size_t)q0 * D_;
    #pragma unroll
    for (int qs = 0; qs < 2; ++qs)
      #pragma unroll
      for (int ds = 0; ds < 2; ++ds) {
        int d = w * 64 + ds * 32 + (lane & 31);
        #pragma unroll
        for (int reg = 0; reg < 16; ++reg) {
          int row = qs * 32 + (reg & 3) + 8 * (reg >> 2) + 4 * (lane >> 5);
          op[(size_t)row * D_ + d] = acc[qs][ds][reg];
        }
      }
  }
}

extern "C" void kernel_launch(void* const* d_in, const int* in_sizes, int n_in,
                              void* d_out, int out_size, void* d_ws, size_t ws_size,
                              hipStream_t stream) {
  const float* tgt = (const float*)d_in[0];
  float* outp = (float*)d_out;

  float*  rn  = (float*)d_ws;                                     // 128 KB
  ushort* Tm2 = (ushort*)((char*)d_ws + (1 << 17));               // 32 MB
  ushort* Vt2 = Tm2 + (size_t)B_ * N_ * D_;                       // 32 MB

  rnorm_kernel<<<dim3((B_ * N_) / 4), dim3(256), 0, stream>>>(tgt, rn);
  prep_kernel<<<dim3(B_ * 64 * 8), dim3(256), 0, stream>>>(tgt, rn, Tm2, Vt2);
  fused_kernel<<<dim3(B_ * (N_ / BM)), dim3(NTH), 0, stream>>>(Tm2, Vt2, outp);
}

// Round 6
// 381.667 us; speedup vs baseline: 1.6667x; 1.6667x over previous
//
#include <hip/hip_runtime.h>
#include <hip/hip_bf16.h>

#define B_ 8
#define N_ 4096
#define D_ 512
#define BM 64
#define BK 64
#define NTH 512
#define NT (N_ / BK)

typedef __attribute__((ext_vector_type(8))) short bf16x8;
typedef __attribute__((ext_vector_type(4))) float f32x4;
typedef __attribute__((ext_vector_type(16))) float f32x16;

__device__ __forceinline__ short f2bs(float x) {
  union { __hip_bfloat16 h; short s; } u;
  u.h = __float2bfloat16(x);
  return u.s;
}

__device__ __forceinline__ void gld16(const void* g, void* l) {
  __builtin_amdgcn_global_load_lds((const __attribute__((address_space(1))) void*)g,
                                   (__attribute__((address_space(3))) void*)l, 16, 0, 0);
}

// ---------------- kernel 1: rn[b*N+n] = 1/||tgt[b,n,:]|| ----------------
__global__ void __launch_bounds__(256) rnorm_kernel(const float* __restrict__ tgt,
                                                    float* __restrict__ rn) {
  int row  = blockIdx.x * 4 + (threadIdx.x >> 6);
  int lane = threadIdx.x & 63;
  const float* p = tgt + (size_t)row * D_ + lane * 8;
  float4 a = *(const float4*)p;
  float4 b = *(const float4*)(p + 4);
  float s = a.x*a.x + a.y*a.y + a.z*a.z + a.w*a.w
          + b.x*b.x + b.y*b.y + b.z*b.z + b.w*b.w;
  #pragma unroll
  for (int m = 32; m >= 1; m >>= 1) s += __shfl_xor(s, m, 64);
  if (lane == 0) rn[row] = rsqrtf(s);
}

// ---------------- kernel 2: prep granule-8 layouts (round-4 proven) ----------------
// Tbf2[b][d>>3][n][d&7] = bf16( tgt[b][n][d] * rn[b][n] )   (normalized)
// Vt2 [b][n>>3][d][n&7] = bf16( tgt[b][n][d] )              (raw)
__global__ void __launch_bounds__(256) prep_kernel(const float* __restrict__ tgt,
                                                   const float* __restrict__ rn,
                                                   ushort* __restrict__ Tbf2,
                                                   ushort* __restrict__ Vt2) {
  __shared__ ushort L[64][72];                  // raw bf16 tile, padded
  const int id = blockIdx.x;                    // 8b x 64nt x 8dt
  const int b = id >> 9, nt = (id >> 3) & 63, dt = id & 7;
  const int n0 = nt * 64, d0 = dt * 64;
  const int t = threadIdx.x;
  const float* Tg  = tgt + ((size_t)b * N_ + n0) * D_ + d0;
  const float* rnb = rn + b * N_ + n0;
  ushort* T2 = Tbf2 + (size_t)b * N_ * D_;
  ushort* V2 = Vt2  + (size_t)b * N_ * D_;

  const int r = t >> 3, g = t & 7;              // row-half, d-granule
  #pragma unroll
  for (int p = 0; p < 2; ++p) {
    int row = p * 32 + r;
    const float* src = Tg + (size_t)row * D_ + g * 8;
    float4 f0 = *(const float4*)src;
    float4 f1 = *(const float4*)(src + 4);
    float sc = rnb[row];
    bf16x8 nv;
    nv[0]=f2bs(f0.x*sc); nv[1]=f2bs(f0.y*sc); nv[2]=f2bs(f0.z*sc); nv[3]=f2bs(f0.w*sc);
    nv[4]=f2bs(f1.x*sc); nv[5]=f2bs(f1.y*sc); nv[6]=f2bs(f1.z*sc); nv[7]=f2bs(f1.w*sc);
    *(bf16x8*)(T2 + ((size_t)(d0/8 + g) * N_ + n0 + row) * 8) = nv;
    bf16x8 rv;
    rv[0]=f2bs(f0.x); rv[1]=f2bs(f0.y); rv[2]=f2bs(f0.z); rv[3]=f2bs(f0.w);
    rv[4]=f2bs(f1.x); rv[5]=f2bs(f1.y); rv[6]=f2bs(f1.z); rv[7]=f2bs(f1.w);
    #pragma unroll
    for (int e = 0; e < 8; ++e) L[row][g*8 + e] = (ushort)rv[e];
  }
  __syncthreads();
  #pragma unroll
  for (int p = 0; p < 2; ++p) {
    int task = p * 256 + t;
    int ng = task >> 6, dd = task & 63;
    bf16x8 v;
    #pragma unroll
    for (int j = 0; j < 8; ++j) v[j] = (short)L[ng*8 + j][dd];
    *(bf16x8*)(V2 + ((size_t)(n0/8 + ng) * D_ + d0 + dd) * 8) = v;
  }
}

// ---------------- kernel 3: fused  out = tanh(Xn Xn^T) * tgt ----------------
// BM=64 q-rows/block, 8 waves, all operands via LDS (round-4 skeleton).
// S: 16x16x32, grid 2q x 4m — Q in regs (2 frags, 128 VGPR), each K B-frag
//    read feeds 2 MFMAs (dup 2x). PV: 32x32x16, grid 1q x 8d — wave owns
//    64q x 64d, V read exactly once. 256 ds_read_b128/tile (was 416).
__global__ void __launch_bounds__(NTH, 2) fused_kernel(const ushort* __restrict__ Tbf2,
                                                       const ushort* __restrict__ Vt2,
                                                       float* __restrict__ out) {
  __shared__ __align__(16) ushort KV[BK * D_];   // [d/8][m][8] normalized  64 KB
  __shared__ __align__(16) ushort VT[BK * D_];   // [m/8][d][8] raw         64 KB
  __shared__ __align__(16) ushort Pl[BM * BK];   // [m/8][q][8]              8 KB

  const int id = blockIdx.x;             // 512 blocks
  const int b  = id & 7;                 // batch -> XCD round-robin
  const int q0 = (id >> 3) * BM;

  const int lane = threadIdx.x & 63;
  const int w    = threadIdx.x >> 6;

  const ushort* Tb2 = Tbf2 + (size_t)b * N_ * D_;  // [d/8][n][8] normalized
  const ushort* Vb2 = Vt2  + (size_t)b * N_ * D_;  // [n/8][d][8] raw

  // ---- S mapping: wave -> q rows [qG*32,+32), m cols [mG*16,+16)
  const int qG = w >> 2;                 // 0..1
  const int mG = w & 3;                  // 0..3

  // Q fragments: 32 rows x 512 d = 128 VGPR
  bf16x8 qf[2][16];
  #pragma unroll
  for (int f = 0; f < 2; ++f) {
    const int row = q0 + qG * 32 + f * 16 + (lane & 15);
    #pragma unroll
    for (int kk = 0; kk < 16; ++kk) {
      int g = kk * 4 + (lane >> 4);
      qf[f][kk] = *(const bf16x8*)(Tb2 + ((size_t)g * N_ + row) * 8);
    }
  }

  f32x16 acc[2][2] = {};                 // wave tile 64q x 64d (d-cols [w*64,+64))

  // stage K-tile: KV[g][m][e] <- Tb2[g][m0+m][e] ; wave w: granules g = w*8..w*8+7
  auto STAGE_KV = [&](int mt) {
    #pragma unroll
    for (int i = 0; i < 8; ++i) {
      int g = w * 8 + i;
      gld16(Tb2 + ((size_t)g * N_ + mt * BK) * 8 + lane * 8, &KV[g * 512]);
    }
  };
  // stage V-tile: VT[mg][d][e] <- Vb2[mt*8+mg][d][e] ; wave w: mg = w
  auto STAGE_VT = [&](int mt) {
    #pragma unroll
    for (int i = 0; i < 8; ++i)
      gld16(Vb2 + ((size_t)(mt * 8 + w) * D_) * 8 + i * 512 + lane * 8,
            &VT[w * 4096 + i * 512]);
  };

  STAGE_KV(0);
  STAGE_VT(0);
  __syncthreads();

  for (int t = 0; t < NT; ++t) {
    // ---- S = Qn * Kn^T : 16 B-reads, 32 MFMA-16x16 per wave
    f32x4 sacc[2] = {};
    #pragma unroll
    for (int kk = 0; kk < 16; ++kk) {
      int g = kk * 4 + (lane >> 4);
      bf16x8 bfr = *(const bf16x8*)&KV[g * 512 + (mG * 16 + (lane & 15)) * 8];
      sacc[0] = __builtin_amdgcn_mfma_f32_16x16x32_bf16(qf[0][kk], bfr, sacc[0], 0, 0, 0);
      sacc[1] = __builtin_amdgcn_mfma_f32_16x16x32_bf16(qf[1][kk], bfr, sacc[1], 0, 0, 0);
    }

    // ---- tanh -> Pl ([m/8][q][8])
    {
      const int mm = mG * 16 + (lane & 15);
      #pragma unroll
      for (int f = 0; f < 2; ++f)
        #pragma unroll
        for (int j = 0; j < 4; ++j) {
          int ql = qG * 32 + f * 16 + (lane >> 4) * 4 + j;
          float e = __builtin_amdgcn_exp2f(sacc[f][j] * 2.885390082f);  // e^(2s)
          float tn = 1.0f - 2.0f * __builtin_amdgcn_rcpf(e + 1.0f);
          Pl[(mm >> 3) * 512 + ql * 8 + (mm & 7)] = (ushort)f2bs(tn);
        }
    }
    __syncthreads();                     // bar1: Pl visible; VT(t) drained

    if (t < NT - 1) STAGE_KV(t + 1);     // lands during PV, drained at bar2

    // ---- out += P * V : 8 A-reads + 8 B-reads, 16 MFMA-32x32 per wave
    #pragma unroll
    for (int ks = 0; ks < 4; ++ks) {
      int gsel = ks * 2 + (lane >> 5);
      bf16x8 pa0 = *(const bf16x8*)&Pl[gsel * 512 + (lane & 31) * 8];
      bf16x8 pa1 = *(const bf16x8*)&Pl[gsel * 512 + (32 + (lane & 31)) * 8];
      bf16x8 vb0 = *(const bf16x8*)&VT[gsel * 4096 + (w * 64 + (lane & 31)) * 8];
      bf16x8 vb1 = *(const bf16x8*)&VT[gsel * 4096 + (w * 64 + 32 + (lane & 31)) * 8];
      acc[0][0] = __builtin_amdgcn_mfma_f32_32x32x16_bf16(pa0, vb0, acc[0][0], 0, 0, 0);
      acc[0][1] = __builtin_amdgcn_mfma_f32_32x32x16_bf16(pa0, vb1, acc[0][1], 0, 0, 0);
      acc[1][0] = __builtin_amdgcn_mfma_f32_32x32x16_bf16(pa1, vb0, acc[1][0], 0, 0, 0);
      acc[1][1] = __builtin_amdgcn_mfma_f32_32x32x16_bf16(pa1, vb1, acc[1][1], 0, 0, 0);
    }
    __syncthreads();                     // bar2: PV done; KV(t+1) drained; VT free

    if (t < NT - 1) STAGE_VT(t + 1);     // lands during S(t+1), drained at bar1
  }

  // ---- write out [64 x 512] fp32; C/D 32x32: row=(reg&3)+8*(reg>>2)+4*(lane>>5)
  {
    float* op = out + (size_t)b * N_ * D_ + (size_t)q0 * D_;
    #pragma unroll
    for (int qs = 0; qs < 2; ++qs)
      #pragma unroll
      for (int ds = 0; ds < 2; ++ds) {
        int d = w * 64 + ds * 32 + (lane & 31);
        #pragma unroll
        for (int reg = 0; reg < 16; ++reg) {
          int row = qs * 32 + (reg & 3) + 8 * (reg >> 2) + 4 * (lane >> 5);
          op[(size_t)row * D_ + d] = acc[qs][ds][reg];
        }
      }
  }
}

extern "C" void kernel_launch(void* const* d_in, const int* in_sizes, int n_in,
                              void* d_out, int out_size, void* d_ws, size_t ws_size,
                              hipStream_t stream) {
  const float* tgt = (const float*)d_in[0];
  float* outp = (float*)d_out;

  float*  rn   = (float*)d_ws;                                    // 128 KB
  ushort* Tbf2 = (ushort*)((char*)d_ws + (1 << 17));              // 32 MB
  ushort* Vt2  = Tbf2 + (size_t)B_ * N_ * D_;                     // 32 MB

  rnorm_kernel<<<dim3((B_ * N_) / 4), dim3(256), 0, stream>>>(tgt, rn);
  prep_kernel<<<dim3(B_ * 64 * 8), dim3(256), 0, stream>>>(tgt, rn, Tbf2, Vt2);
  fused_kernel<<<dim3(B_ * (N_ / BM)), dim3(NTH), 0, stream>>>(Tbf2, Vt2, outp);
}

// Round 7
// 348.649 us; speedup vs baseline: 1.8245x; 1.0947x over previous
//
#include <hip/hip_runtime.h>
#include <hip/hip_bf16.h>

#define B_ 8
#define N_ 4096
#define D_ 512
#define BM 64
#define BK 64
#define NTH 512
#define NT (N_ / BK)

typedef __attribute__((ext_vector_type(8))) short bf16x8;
typedef __attribute__((ext_vector_type(4))) float f32x4;
typedef __attribute__((ext_vector_type(16))) float f32x16;

__device__ __forceinline__ short f2bs(float x) {
  union { __hip_bfloat16 h; short s; } u;
  u.h = __float2bfloat16(x);
  return u.s;
}

__device__ __forceinline__ void gld16(const void* g, void* l) {
  __builtin_amdgcn_global_load_lds((const __attribute__((address_space(1))) void*)g,
                                   (__attribute__((address_space(3))) void*)l, 16, 0, 0);
}

// ---------------- kernel 1: rn[b*N+n] = 1/||tgt[b,n,:]|| ----------------
__global__ void __launch_bounds__(256) rnorm_kernel(const float* __restrict__ tgt,
                                                    float* __restrict__ rn) {
  int row  = blockIdx.x * 4 + (threadIdx.x >> 6);
  int lane = threadIdx.x & 63;
  const float* p = tgt + (size_t)row * D_ + lane * 8;
  float4 a = *(const float4*)p;
  float4 b = *(const float4*)(p + 4);
  float s = a.x*a.x + a.y*a.y + a.z*a.z + a.w*a.w
          + b.x*b.x + b.y*b.y + b.z*b.z + b.w*b.w;
  #pragma unroll
  for (int m = 32; m >= 1; m >>= 1) s += __shfl_xor(s, m, 64);
  if (lane == 0) rn[row] = rsqrtf(s);
}

// ---------------- kernel 2: prep granule-8 layouts ----------------
// Tbf2[b][d>>3][n][d&7] = bf16( tgt[b][n][d] * rn[b][n] )   (normalized)
// Vt2 [b][n>>3][d][n&7] = bf16( tgt[b][n][d] )              (raw)
__global__ void __launch_bounds__(256) prep_kernel(const float* __restrict__ tgt,
                                                   const float* __restrict__ rn,
                                                   ushort* __restrict__ Tbf2,
                                                   ushort* __restrict__ Vt2) {
  __shared__ ushort L[64][72];                  // raw bf16 tile, padded
  const int id = blockIdx.x;                    // 8b x 64nt x 8dt
  const int b = id >> 9, nt = (id >> 3) & 63, dt = id & 7;
  const int n0 = nt * 64, d0 = dt * 64;
  const int t = threadIdx.x;
  const float* Tg  = tgt + ((size_t)b * N_ + n0) * D_ + d0;
  const float* rnb = rn + b * N_ + n0;
  ushort* T2 = Tbf2 + (size_t)b * N_ * D_;
  ushort* V2 = Vt2  + (size_t)b * N_ * D_;

  const int r = t >> 3, g = t & 7;              // row-half, d-granule
  #pragma unroll
  for (int p = 0; p < 2; ++p) {
    int row = p * 32 + r;
    const float* src = Tg + (size_t)row * D_ + g * 8;
    float4 f0 = *(const float4*)src;
    float4 f1 = *(const float4*)(src + 4);
    float sc = rnb[row];
    bf16x8 nv;
    nv[0]=f2bs(f0.x*sc); nv[1]=f2bs(f0.y*sc); nv[2]=f2bs(f0.z*sc); nv[3]=f2bs(f0.w*sc);
    nv[4]=f2bs(f1.x*sc); nv[5]=f2bs(f1.y*sc); nv[6]=f2bs(f1.z*sc); nv[7]=f2bs(f1.w*sc);
    *(bf16x8*)(T2 + ((size_t)(d0/8 + g) * N_ + n0 + row) * 8) = nv;
    bf16x8 rv;
    rv[0]=f2bs(f0.x); rv[1]=f2bs(f0.y); rv[2]=f2bs(f0.z); rv[3]=f2bs(f0.w);
    rv[4]=f2bs(f1.x); rv[5]=f2bs(f1.y); rv[6]=f2bs(f1.z); rv[7]=f2bs(f1.w);
    #pragma unroll
    for (int e = 0; e < 8; ++e) L[row][g*8 + e] = (ushort)rv[e];
  }
  __syncthreads();
  #pragma unroll
  for (int p = 0; p < 2; ++p) {
    int task = p * 256 + t;
    int ng = task >> 6, dd = task & 63;
    bf16x8 v;
    #pragma unroll
    for (int j = 0; j < 8; ++j) v[j] = (short)L[ng*8 + j][dd];
    *(bf16x8*)(V2 + ((size_t)(n0/8 + ng) * D_ + d0 + dd) * 8) = v;
  }
}

// ---------------- kernel 3: fused  out = tanh(Xn Xn^T) * tgt ----------------
// r4 skeleton. S: 16x16x32 grid 4q x 2m (qf[16], 64 VGPR). PV: 32x32x16,
// grid 1q x 8d (r6). All LDS read addrs = single base + imm offsets; staging
// pointers hoisted (const increments). setprio around MFMA clusters.
__global__ void __launch_bounds__(NTH, 2) fused_kernel(const ushort* __restrict__ Tbf2,
                                                       const ushort* __restrict__ Vt2,
                                                       float* __restrict__ out) {
  __shared__ __align__(16) ushort KV[BK * D_];   // [d/8][m][8] normalized  64 KB
  __shared__ __align__(16) ushort VT[BK * D_];   // [m/8][d][8] raw         64 KB
  __shared__ __align__(16) ushort Pl[BM * BK];   // [m/8][q][8]              8 KB

  const int id = blockIdx.x;             // 512 blocks
  const int b  = id & 7;                 // batch -> XCD round-robin
  const int q0 = (id >> 3) * BM;

  const int lane = threadIdx.x & 63;
  const int w    = threadIdx.x >> 6;

  const ushort* Tb2 = Tbf2 + (size_t)b * N_ * D_;  // [d/8][n][8] normalized
  const ushort* Vb2 = Vt2  + (size_t)b * N_ * D_;  // [n/8][d][8] raw

  // ---- S mapping (r4): wave -> q rows [qG*16,+16), m cols [mG*32,+32)
  const int qG = w >> 1;                 // 0..3
  const int mG = w & 1;                  // 0..1

  // Q fragments: 16 rows x 512 d = 64 VGPR
  bf16x8 qf[16];
  {
    const int row = q0 + qG * 16 + (lane & 15);
    #pragma unroll
    for (int kk = 0; kk < 16; ++kk) {
      int g = kk * 4 + (lane >> 4);
      qf[kk] = *(const bf16x8*)(Tb2 + ((size_t)g * N_ + row) * 8);
    }
  }

  f32x16 acc[2][2] = {};                 // wave tile 64q x 64d (d-cols [w*64,+64))

  // ---- hoisted LDS read bases (ushort indices; all loop offsets are consts)
  const ushort* kvrd = &KV[(lane >> 4) * 512 + (mG * 32 + (lane & 15)) * 8];
  const ushort* pard = &Pl[(lane >> 5) * 512 + (lane & 31) * 8];
  const ushort* vbrd = &VT[(lane >> 5) * 4096 + (w * 64 + (lane & 31)) * 8];
  ushort*       plwr = &Pl[((mG * 32 + (lane & 15)) >> 3) * 512
                           + (qG * 16 + (lane >> 4) * 4) * 8
                           + ((lane & 15) & 7)];

  // ---- hoisted staging pointers (advance by constants each tile)
  const ushort* kvsrc = Tb2 + (size_t)(w * 8) * N_ * 8 + (size_t)BK * 8 + lane * 8;
  const ushort* vtsrc = Vb2 + (size_t)(8 + w) * D_ * 8 + lane * 8;

  // prologue: stage tile 0
  #pragma unroll
  for (int i = 0; i < 8; ++i)
    gld16(Tb2 + ((size_t)(w * 8 + i) * N_) * 8 + lane * 8, &KV[(w * 8 + i) * 512]);
  #pragma unroll
  for (int i = 0; i < 8; ++i)
    gld16(Vb2 + (size_t)w * D_ * 8 + i * 512 + lane * 8, &VT[w * 4096 + i * 512]);
  __syncthreads();

  for (int t = 0; t < NT; ++t) {
    // ---- S = Qn * Kn^T : 32 reads (imm offsets), 32 MFMA-16x16 per wave
    f32x4 sacc[2] = {};
    __builtin_amdgcn_s_setprio(1);
    #pragma unroll
    for (int kk = 0; kk < 16; ++kk) {
      bf16x8 b0 = *(const bf16x8*)(kvrd + kk * 2048);
      bf16x8 b1 = *(const bf16x8*)(kvrd + kk * 2048 + 128);
      sacc[0] = __builtin_amdgcn_mfma_f32_16x16x32_bf16(qf[kk], b0, sacc[0], 0, 0, 0);
      sacc[1] = __builtin_amdgcn_mfma_f32_16x16x32_bf16(qf[kk], b1, sacc[1], 0, 0, 0);
    }
    __builtin_amdgcn_s_setprio(0);

    // ---- tanh -> Pl ([m/8][q][8])
    #pragma unroll
    for (int f = 0; f < 2; ++f)
      #pragma unroll
      for (int j = 0; j < 4; ++j) {
        float e = __builtin_amdgcn_exp2f(sacc[f][j] * 2.885390082f);  // e^(2s)
        float tn = 1.0f - 2.0f * __builtin_amdgcn_rcpf(e + 1.0f);
        plwr[f * 1024 + j * 8] = (ushort)f2bs(tn);
      }
    __syncthreads();                     // bar1: Pl visible; VT(t) drained

    if (t < NT - 1) {                    // stage KV(t+1), lands during PV
      #pragma unroll
      for (int i = 0; i < 8; ++i)
        gld16(kvsrc + (size_t)i * N_ * 8, &KV[(w * 8 + i) * 512]);
      kvsrc += BK * 8;                   // +1 KB
    }

    // ---- out += P * V : 16 reads (imm offsets), 16 MFMA-32x32 per wave
    __builtin_amdgcn_s_setprio(1);
    #pragma unroll
    for (int ks = 0; ks < 4; ++ks) {
      bf16x8 pa0 = *(const bf16x8*)(pard + ks * 1024);
      bf16x8 pa1 = *(const bf16x8*)(pard + ks * 1024 + 256);
      bf16x8 vb0 = *(const bf16x8*)(vbrd + ks * 8192);
      bf16x8 vb1 = *(const bf16x8*)(vbrd + ks * 8192 + 256);
      acc[0][0] = __builtin_amdgcn_mfma_f32_32x32x16_bf16(pa0, vb0, acc[0][0], 0, 0, 0);
      acc[0][1] = __builtin_amdgcn_mfma_f32_32x32x16_bf16(pa0, vb1, acc[0][1], 0, 0, 0);
      acc[1][0] = __builtin_amdgcn_mfma_f32_32x32x16_bf16(pa1, vb0, acc[1][0], 0, 0, 0);
      acc[1][1] = __builtin_amdgcn_mfma_f32_32x32x16_bf16(pa1, vb1, acc[1][1], 0, 0, 0);
    }
    __builtin_amdgcn_s_setprio(0);
    __syncthreads();                     // bar2: PV done; KV(t+1) drained; VT free

    if (t < NT - 1) {                    // stage VT(t+1), lands during S(t+1)
      #pragma unroll
      for (int i = 0; i < 8; ++i)
        gld16(vtsrc + i * 512, &VT[w * 4096 + i * 512]);
      vtsrc += 8 * D_ * 8;               // +64 KB
    }
  }

  // ---- write out [64 x 512] fp32; C/D 32x32: row=(reg&3)+8*(reg>>2)+4*(lane>>5)
  {
    float* op = out + (size_t)b * N_ * D_ + (size_t)q0 * D_;
    #pragma unroll
    for (int qs = 0; qs < 2; ++qs)
      #pragma unroll
      for (int ds = 0; ds < 2; ++ds) {
        int d = w * 64 + ds * 32 + (lane & 31);
        #pragma unroll
        for (int reg = 0; reg < 16; ++reg) {
          int row = qs * 32 + (reg & 3) + 8 * (reg >> 2) + 4 * (lane >> 5);
          op[(size_t)row * D_ + d] = acc[qs][ds][reg];
        }
      }
  }
}

extern "C" void kernel_launch(void* const* d_in, const int* in_sizes, int n_in,
                              void* d_out, int out_size, void* d_ws, size_t ws_size,
                              hipStream_t stream) {
  const float* tgt = (const float*)d_in[0];
  float* outp = (float*)d_out;

  float*  rn   = (float*)d_ws;                                    // 128 KB
  ushort* Tbf2 = (ushort*)((char*)d_ws + (1 << 17));              // 32 MB
  ushort* Vt2  = Tbf2 + (size_t)B_ * N_ * D_;                     // 32 MB

  rnorm_kernel<<<dim3((B_ * N_) / 4), dim3(256), 0, stream>>>(tgt, rn);
  prep_kernel<<<dim3(B_ * 64 * 8), dim3(256), 0, stream>>>(tgt, rn, Tbf2, Vt2);
  fused_kernel<<<dim3(B_ * (N_ / BM)), dim3(NTH), 0, stream>>>(Tbf2, Vt2, outp);
}